// Round 9
// baseline (71.803 us; speedup 1.0000x reference)
//
#include <hip/hip_runtime.h>

#define VOCAB 30522
#define D     768
#define NC    9
#define NROWS 16384          // 32*512
#define TPB   256

#define G_ROW 1024           // 4 waves/block * 4 rows/wave * 1024 = 16384 rows
#define RPW   4              // rows per wave (16 waves/CU at 4 blocks/CU)

#define G_FIN   256          // all 256 CUs busy
#define TPB_FIN 1024         // 16 waves/block
#define SLICE   120          // 256 * 120 = 30720 >= VOCAB
#define NITER   (NROWS / 4 / TPB_FIN)   // 4

typedef float v2f __attribute__((ext_vector_type(2)));

// Workspace (floats): means[NROWS] | wsum2[16]   (65600 B << ws_size)

// ---------------------------------------------------------------------------
// Full-wave (64-lane) sum via DPP — pure VALU. Result valid in lane 63.
// (Sequence numerically validated rounds 2-8.)
// ---------------------------------------------------------------------------
__device__ __forceinline__ float wave_reduce_add(float x) {
#define DPP_STEP(ctrl)                                                         \
    do {                                                                       \
        int t_ = __builtin_amdgcn_update_dpp(0, __float_as_int(x), (ctrl),     \
                                             0xf, 0xf, true);                  \
        x += __int_as_float(t_);                                               \
    } while (0)
    DPP_STEP(0x111); DPP_STEP(0x112); DPP_STEP(0x114); DPP_STEP(0x118);
    DPP_STEP(0x142); DPP_STEP(0x143);
#undef DPP_STEP
    return x;
}

// wsum2[c] = sum_{d>=768} W[d,c].  Waves 0..3; lane-63 writes.
__device__ __forceinline__ void compute_wsum2(const float* __restrict__ W,
                                              int lane, int wave, float* dst) {
    float s0 = 0.f, s1 = 0.f, s2 = 0.f;
    #pragma unroll
    for (int k = 0; k < 12; ++k) {
        const float* rw = W + (size_t)(D + lane + 64 * k) * NC;
        s0 += rw[wave];
        s1 += rw[wave + 4];
        if (wave == 0) s2 += rw[8];
    }
    s0 = wave_reduce_add(s0);
    s1 = wave_reduce_add(s1);
    s2 = wave_reduce_add(s2);
    if (lane == 63) {
        dst[wave]     = s0;
        dst[wave + 4] = s1;
        if (wave == 0) dst[8] = s2;
    }
}

// FMA one 4-dim chunk: v = h values for dims d..d+3; wk[j][p] = W'[d+j] column
// pair p (cols 2p,2p+1; p=4 -> {col8, ones}).
__device__ __forceinline__ void fma4(v2f (&acc)[5], float4 v,
                                     const v2f (&wk)[4][5]) {
    const float vv[4] = {v.x, v.y, v.z, v.w};
    #pragma unroll
    for (int j = 0; j < 4; ++j) {
        const v2f b = {vv[j], vv[j]};
        #pragma unroll
        for (int p = 0; p < 5; ++p)
            acc[p] = __builtin_elementwise_fma(b, wk[j][p], acc[p]);
    }
}

// ---------------------------------------------------------------------------
// Row pass: 1024 blocks x 4 waves, 4 rows/wave (16 waves/CU for latency
// hiding).  Same streaming core: 2-row compute, depth-1 prefetch.
// Lane 63 writes 9 dots -> out, row mean -> means[].  Block 0 also computes
// wsum2 into ws for the finalize kernel.
// ---------------------------------------------------------------------------
__global__ __launch_bounds__(TPB, 4) void row_kernel(
    const float* __restrict__ h, const float* __restrict__ W,
    float* __restrict__ means, float* __restrict__ wsum2,
    float* __restrict__ out)
{
    const int lane = threadIdx.x & 63;
    const int wave = threadIdx.x >> 6;
    const int base = (blockIdx.x * 4 + wave) * RPW;

    v2f wf[3][4][5];
    #pragma unroll
    for (int k = 0; k < 3; ++k) {
        const float4* wp = (const float4*)W + (size_t)(lane + 64 * k) * 9;
        float w36[36];
        #pragma unroll
        for (int i = 0; i < 9; ++i) {
            float4 v = wp[i];
            w36[4*i+0] = v.x; w36[4*i+1] = v.y; w36[4*i+2] = v.z; w36[4*i+3] = v.w;
        }
        #pragma unroll
        for (int j = 0; j < 4; ++j) {
            #pragma unroll
            for (int p = 0; p < 4; ++p)
                wf[k][j][p] = (v2f){w36[j*9 + 2*p], w36[j*9 + 2*p + 1]};
            wf[k][j][4] = (v2f){w36[j*9 + 8], 1.0f};
        }
    }

    const float4* hb = (const float4*)h + (size_t)base * (D / 4) + lane;
#define LDROW(rr, V0, V1, V2)                                                  \
    do { const float4* hp_ = hb + (size_t)(rr) * (D / 4);                      \
         V0 = hp_[0]; V1 = hp_[64]; V2 = hp_[128]; } while (0)

    float4 A0, A1, A2, B0, B1, B2;
    LDROW(0, A0, A1, A2);
    LDROW(1, B0, B1, B2);

    #pragma unroll
    for (int rp = 0; rp < RPW / 2; ++rp) {
        float4 N0, N1, N2, M0, M1, M2;
        if (rp < RPW / 2 - 1) {
            LDROW(2 * rp + 2, N0, N1, N2);
            LDROW(2 * rp + 3, M0, M1, M2);
        }
        const int rA = base + 2 * rp, rB = rA + 1;

        v2f accA[5], accB[5];
        #pragma unroll
        for (int p = 0; p < 5; ++p) {
            accA[p] = (v2f){0.f, 0.f};
            accB[p] = (v2f){0.f, 0.f};
        }
        fma4(accA, A0, wf[0]); fma4(accA, A1, wf[1]); fma4(accA, A2, wf[2]);
        fma4(accB, B0, wf[0]); fma4(accB, B1, wf[1]); fma4(accB, B2, wf[2]);

        float ra[10] = {accA[0].x, accA[0].y, accA[1].x, accA[1].y, accA[2].x,
                        accA[2].y, accA[3].x, accA[3].y, accA[4].x, accA[4].y};
        float rb[10] = {accB[0].x, accB[0].y, accB[1].x, accB[1].y, accB[2].x,
                        accB[2].y, accB[3].x, accB[3].y, accB[4].x, accB[4].y};
        #pragma unroll
        for (int t = 0; t < 10; ++t) {
            ra[t] = wave_reduce_add(ra[t]);
            rb[t] = wave_reduce_add(rb[t]);
        }

        if (lane == 63) {
            float* oA = out + (size_t)rA * NC;
            float* oB = out + (size_t)rB * NC;
            #pragma unroll
            for (int c = 0; c < 9; ++c) { oA[c] = ra[c]; oB[c] = rb[c]; }
            means[rA] = ra[9] * (1.f / 768.f);
            means[rB] = rb[9] * (1.f / 768.f);
        }

        if (rp < RPW / 2 - 1) {
            A0 = N0; A1 = N1; A2 = N2;
            B0 = M0; B1 = M1; B2 = M2;
        }
    }
#undef LDROW

    if (blockIdx.x == 0)
        compute_wsum2(W, lane, wave, wsum2);
}

// ---------------------------------------------------------------------------
// Finalize: 256 blocks (ALL CUs) x 1024 threads (16 waves/CU TLP); block b
// owns vocab slice [b*120, b*120+120).
//   scan 1: 4 unrolled int4/float4 iterations — 8 independent loads in
//           flight per thread before any dependent LDS atomic.
//   scan 2: int4 ids; matching rows RMW out[row,:]  (~0.8% match rate).
// ---------------------------------------------------------------------------
__global__ __launch_bounds__(TPB_FIN) void finalize_kernel(
    const int* __restrict__ ids, const float* __restrict__ means,
    const float* __restrict__ wsum2, const float* __restrict__ bias,
    float* __restrict__ out)
{
    __shared__ float s_sum[SLICE];
    __shared__ float s_cnt[SLICE];

    const int tid = threadIdx.x;
    const int lo  = blockIdx.x * SLICE;

    if (tid < SLICE) { s_sum[tid] = 0.f; s_cnt[tid] = 0.f; }
    __syncthreads();

    const int4*   ids4   = (const int4*)ids;
    const float4* means4 = (const float4*)means;

    // ---- scan 1: issue all 8 loads, then aggregate.
    int4   iv[NITER];
    float4 mv[NITER];
    #pragma unroll
    for (int k = 0; k < NITER; ++k) {
        const int q = tid + k * TPB_FIN;
        iv[k] = ids4[q];
        mv[k] = means4[q];
    }
    #pragma unroll
    for (int k = 0; k < NITER; ++k) {
        const int k0 = iv[k].x - lo, k1 = iv[k].y - lo,
                  k2 = iv[k].z - lo, k3 = iv[k].w - lo;
        if ((unsigned)k0 < (unsigned)SLICE) { atomicAdd(&s_sum[k0], mv[k].x); atomicAdd(&s_cnt[k0], 1.f); }
        if ((unsigned)k1 < (unsigned)SLICE) { atomicAdd(&s_sum[k1], mv[k].y); atomicAdd(&s_cnt[k1], 1.f); }
        if ((unsigned)k2 < (unsigned)SLICE) { atomicAdd(&s_sum[k2], mv[k].z); atomicAdd(&s_cnt[k2], 1.f); }
        if ((unsigned)k3 < (unsigned)SLICE) { atomicAdd(&s_sum[k3], mv[k].w); atomicAdd(&s_cnt[k3], 1.f); }
    }
    __syncthreads();

    // sums -> means (one divide per slice entry)
    if (tid < SLICE) s_sum[tid] = s_sum[tid] / fmaxf(s_cnt[tid], 1.f);
    __syncthreads();

    // hoist wsum2/bias into registers
    float wv[NC], bv[NC];
    #pragma unroll
    for (int c = 0; c < NC; ++c) { wv[c] = wsum2[c]; bv[c] = bias[c]; }

    // ---- scan 2: apply to this slice's rows.
    #pragma unroll
    for (int k = 0; k < NITER; ++k) {
        const int kk[4] = {iv[k].x - lo, iv[k].y - lo, iv[k].z - lo, iv[k].w - lo};
        #pragma unroll
        for (int j = 0; j < 4; ++j) {
            if ((unsigned)kk[j] < (unsigned)SLICE) {
                const int q = tid + k * TPB_FIN;
                const float ctx = s_sum[kk[j]];
                float* op = out + (size_t)(4 * q + j) * NC;
                #pragma unroll
                for (int c = 0; c < NC; ++c)
                    op[c] += fmaf(ctx, wv[c], bv[c]);
            }
        }
    }
}

extern "C" void kernel_launch(void* const* d_in, const int* in_sizes, int n_in,
                              void* d_out, int out_size, void* d_ws, size_t ws_size,
                              hipStream_t stream) {
    const int*   ids = (const int*)  d_in[0];  // [32,512] int32
    const float* h   = (const float*)d_in[1];  // [32,512,768] f32
    const float* W   = (const float*)d_in[2];  // [1536,9] f32
    const float* b   = (const float*)d_in[3];  // [9] f32
    float* out = (float*)d_out;                // [32,512,9] f32

    float* means = (float*)d_ws;               // [NROWS]
    float* wsum2 = means + NROWS;              // [16]

    row_kernel<<<G_ROW, TPB, 0, stream>>>(h, W, means, wsum2, out);
    finalize_kernel<<<G_FIN, TPB_FIN, 0, stream>>>(ids, means, wsum2, b, out);
}

// Round 10
// 24.846 us; speedup vs baseline: 2.8900x; 2.8900x over previous
//
#include <hip/hip_runtime.h>

#define VOCAB 30522
#define D     768
#define NC    9
#define NROWS 16384          // 32*512
#define TPB   256

#define G_ROW 512            // 4 waves/block * 8 rows/wave * 512 = 16384 rows
#define RPW   8              // rows per wave

#define G_FIN   256          // all 256 CUs busy
#define TPB_FIN 1024         // 16 waves/block
#define SLICE   120          // 256 * 120 = 30720 >= VOCAB
#define NITER   (NROWS / 4 / TPB_FIN)   // 4

typedef float v2f __attribute__((ext_vector_type(2)));

// Workspace (floats): means[NROWS] | wsum2[16]   (65600 B << ws_size)

// ---------------------------------------------------------------------------
// Full-wave (64-lane) sum via DPP — pure VALU. Result valid in lane 63.
// (Sequence numerically validated rounds 2-9.)
// ---------------------------------------------------------------------------
__device__ __forceinline__ float wave_reduce_add(float x) {
#define DPP_STEP(ctrl)                                                         \
    do {                                                                       \
        int t_ = __builtin_amdgcn_update_dpp(0, __float_as_int(x), (ctrl),     \
                                             0xf, 0xf, true);                  \
        x += __int_as_float(t_);                                               \
    } while (0)
    DPP_STEP(0x111); DPP_STEP(0x112); DPP_STEP(0x114); DPP_STEP(0x118);
    DPP_STEP(0x142); DPP_STEP(0x143);
#undef DPP_STEP
    return x;
}

// wsum2[c] = sum_{d>=768} W[d,c].  Waves 0..3; lane-63 writes.
__device__ __forceinline__ void compute_wsum2(const float* __restrict__ W,
                                              int lane, int wave, float* dst) {
    float s0 = 0.f, s1 = 0.f, s2 = 0.f;
    #pragma unroll
    for (int k = 0; k < 12; ++k) {
        const float* rw = W + (size_t)(D + lane + 64 * k) * NC;
        s0 += rw[wave];
        s1 += rw[wave + 4];
        if (wave == 0) s2 += rw[8];
    }
    s0 = wave_reduce_add(s0);
    s1 = wave_reduce_add(s1);
    s2 = wave_reduce_add(s2);
    if (lane == 63) {
        dst[wave]     = s0;
        dst[wave + 4] = s1;
        if (wave == 0) dst[8] = s2;
    }
}

// FMA one 4-dim chunk: v = h values for dims d..d+3; wk[j][p] = W'[d+j] column
// pair p (cols 2p,2p+1; p=4 -> {col8, ones}).
__device__ __forceinline__ void fma4(v2f (&acc)[5], float4 v,
                                     const v2f (&wk)[4][5]) {
    const float vv[4] = {v.x, v.y, v.z, v.w};
    #pragma unroll
    for (int j = 0; j < 4; ++j) {
        const v2f b = {vv[j], vv[j]};
        #pragma unroll
        for (int p = 0; p < 5; ++p)
            acc[p] = __builtin_elementwise_fma(b, wk[j][p], acc[p]);
    }
}

// ---------------------------------------------------------------------------
// Row pass — EXACT R6/R7 config (512 blocks, 8 rows/wave, launch_bounds(256,2)
// so the 120-float W fragment stays in registers; R9's (256,4) capped VGPRs
// at 64 and spilled it to scratch: FETCH 105 MB / WRITE 138 MB).
// Lane 63 writes 9 dots -> out, row mean -> means[].  Block 0 also computes
// wsum2 into ws for the finalize kernel.
// ---------------------------------------------------------------------------
__global__ __launch_bounds__(TPB, 2) void row_kernel(
    const float* __restrict__ h, const float* __restrict__ W,
    float* __restrict__ means, float* __restrict__ wsum2,
    float* __restrict__ out)
{
    const int lane = threadIdx.x & 63;
    const int wave = threadIdx.x >> 6;
    const int base = (blockIdx.x * 4 + wave) * RPW;

    v2f wf[3][4][5];
    #pragma unroll
    for (int k = 0; k < 3; ++k) {
        const float4* wp = (const float4*)W + (size_t)(lane + 64 * k) * 9;
        float w36[36];
        #pragma unroll
        for (int i = 0; i < 9; ++i) {
            float4 v = wp[i];
            w36[4*i+0] = v.x; w36[4*i+1] = v.y; w36[4*i+2] = v.z; w36[4*i+3] = v.w;
        }
        #pragma unroll
        for (int j = 0; j < 4; ++j) {
            #pragma unroll
            for (int p = 0; p < 4; ++p)
                wf[k][j][p] = (v2f){w36[j*9 + 2*p], w36[j*9 + 2*p + 1]};
            wf[k][j][4] = (v2f){w36[j*9 + 8], 1.0f};
        }
    }

    const float4* hb = (const float4*)h + (size_t)base * (D / 4) + lane;
#define LDROW(rr, V0, V1, V2)                                                  \
    do { const float4* hp_ = hb + (size_t)(rr) * (D / 4);                      \
         V0 = hp_[0]; V1 = hp_[64]; V2 = hp_[128]; } while (0)

    float4 A0, A1, A2, B0, B1, B2;
    LDROW(0, A0, A1, A2);
    LDROW(1, B0, B1, B2);

    #pragma unroll
    for (int rp = 0; rp < RPW / 2; ++rp) {
        float4 N0, N1, N2, M0, M1, M2;
        if (rp < RPW / 2 - 1) {
            LDROW(2 * rp + 2, N0, N1, N2);
            LDROW(2 * rp + 3, M0, M1, M2);
        }
        const int rA = base + 2 * rp, rB = rA + 1;

        v2f accA[5], accB[5];
        #pragma unroll
        for (int p = 0; p < 5; ++p) {
            accA[p] = (v2f){0.f, 0.f};
            accB[p] = (v2f){0.f, 0.f};
        }
        fma4(accA, A0, wf[0]); fma4(accA, A1, wf[1]); fma4(accA, A2, wf[2]);
        fma4(accB, B0, wf[0]); fma4(accB, B1, wf[1]); fma4(accB, B2, wf[2]);

        float ra[10] = {accA[0].x, accA[0].y, accA[1].x, accA[1].y, accA[2].x,
                        accA[2].y, accA[3].x, accA[3].y, accA[4].x, accA[4].y};
        float rb[10] = {accB[0].x, accB[0].y, accB[1].x, accB[1].y, accB[2].x,
                        accB[2].y, accB[3].x, accB[3].y, accB[4].x, accB[4].y};
        #pragma unroll
        for (int t = 0; t < 10; ++t) {
            ra[t] = wave_reduce_add(ra[t]);
            rb[t] = wave_reduce_add(rb[t]);
        }

        if (lane == 63) {
            float* oA = out + (size_t)rA * NC;
            float* oB = out + (size_t)rB * NC;
            #pragma unroll
            for (int c = 0; c < 9; ++c) { oA[c] = ra[c]; oB[c] = rb[c]; }
            means[rA] = ra[9] * (1.f / 768.f);
            means[rB] = rb[9] * (1.f / 768.f);
        }

        if (rp < RPW / 2 - 1) {
            A0 = N0; A1 = N1; A2 = N2;
            B0 = M0; B1 = M1; B2 = M2;
        }
    }
#undef LDROW

    if (blockIdx.x == 0)
        compute_wsum2(W, lane, wave, wsum2);
}

// ---------------------------------------------------------------------------
// Finalize (R9 structure, kept): 256 blocks (ALL CUs) x 1024 threads; block b
// owns vocab slice [b*120, b*120+120).
//   scan 1: all 8 int4/float4 loads issued before any dependent LDS atomic.
//   scan 2: int4 ids; matching rows RMW out[row,:]  (~0.8% match rate).
// ---------------------------------------------------------------------------
__global__ __launch_bounds__(TPB_FIN) void finalize_kernel(
    const int* __restrict__ ids, const float* __restrict__ means,
    const float* __restrict__ wsum2, const float* __restrict__ bias,
    float* __restrict__ out)
{
    __shared__ float s_sum[SLICE];
    __shared__ float s_cnt[SLICE];

    const int tid = threadIdx.x;
    const int lo  = blockIdx.x * SLICE;

    if (tid < SLICE) { s_sum[tid] = 0.f; s_cnt[tid] = 0.f; }
    __syncthreads();

    const int4*   ids4   = (const int4*)ids;
    const float4* means4 = (const float4*)means;

    // ---- scan 1: issue all 8 loads, then aggregate.
    int4   iv[NITER];
    float4 mv[NITER];
    #pragma unroll
    for (int k = 0; k < NITER; ++k) {
        const int q = tid + k * TPB_FIN;
        iv[k] = ids4[q];
        mv[k] = means4[q];
    }
    #pragma unroll
    for (int k = 0; k < NITER; ++k) {
        const int k0 = iv[k].x - lo, k1 = iv[k].y - lo,
                  k2 = iv[k].z - lo, k3 = iv[k].w - lo;
        if ((unsigned)k0 < (unsigned)SLICE) { atomicAdd(&s_sum[k0], mv[k].x); atomicAdd(&s_cnt[k0], 1.f); }
        if ((unsigned)k1 < (unsigned)SLICE) { atomicAdd(&s_sum[k1], mv[k].y); atomicAdd(&s_cnt[k1], 1.f); }
        if ((unsigned)k2 < (unsigned)SLICE) { atomicAdd(&s_sum[k2], mv[k].z); atomicAdd(&s_cnt[k2], 1.f); }
        if ((unsigned)k3 < (unsigned)SLICE) { atomicAdd(&s_sum[k3], mv[k].w); atomicAdd(&s_cnt[k3], 1.f); }
    }
    __syncthreads();

    // sums -> means (one divide per slice entry)
    if (tid < SLICE) s_sum[tid] = s_sum[tid] / fmaxf(s_cnt[tid], 1.f);
    __syncthreads();

    // hoist wsum2/bias into registers
    float wv[NC], bv[NC];
    #pragma unroll
    for (int c = 0; c < NC; ++c) { wv[c] = wsum2[c]; bv[c] = bias[c]; }

    // ---- scan 2: apply to this slice's rows.
    #pragma unroll
    for (int k = 0; k < NITER; ++k) {
        const int kk[4] = {iv[k].x - lo, iv[k].y - lo, iv[k].z - lo, iv[k].w - lo};
        #pragma unroll
        for (int j = 0; j < 4; ++j) {
            if ((unsigned)kk[j] < (unsigned)SLICE) {
                const int q = tid + k * TPB_FIN;
                const float ctx = s_sum[kk[j]];
                float* op = out + (size_t)(4 * q + j) * NC;
                #pragma unroll
                for (int c = 0; c < NC; ++c)
                    op[c] += fmaf(ctx, wv[c], bv[c]);
            }
        }
    }
}

extern "C" void kernel_launch(void* const* d_in, const int* in_sizes, int n_in,
                              void* d_out, int out_size, void* d_ws, size_t ws_size,
                              hipStream_t stream) {
    const int*   ids = (const int*)  d_in[0];  // [32,512] int32
    const float* h   = (const float*)d_in[1];  // [32,512,768] f32
    const float* W   = (const float*)d_in[2];  // [1536,9] f32
    const float* b   = (const float*)d_in[3];  // [9] f32
    float* out = (float*)d_out;                // [32,512,9] f32

    float* means = (float*)d_ws;               // [NROWS]
    float* wsum2 = means + NROWS;              // [16]

    row_kernel<<<G_ROW, TPB, 0, stream>>>(h, W, means, wsum2, out);
    finalize_kernel<<<G_FIN, TPB_FIN, 0, stream>>>(ids, means, wsum2, b, out);
}